// Round 16
// baseline (211.533 us; speedup 1.0000x reference)
//
#include <hip/hip_runtime.h>

constexpr int kNodes = 50000;
constexpr int kEdges = 800000;
constexpr int kNF  = 64;
constexpr int kHid = 64;

constexpr int WRN  = 136;  // nw1t / sN row stride (K=128 pad)
constexpr int WR2n = 72;   // nw2t / sM row stride
constexpr int WL   = 72;   // edge-kernel LDS weight row stride

typedef _Float16 f16x8 __attribute__((ext_vector_type(8)));
typedef float    f32x4 __attribute__((ext_vector_type(4)));

// ---------------------------------------------------------------------------
// Fused prep: h->f16 (+nodein low half), coord/vel pack, edge histogram,
// weight transposes. w1t has e_b1 folded at k=131.
// ---------------------------------------------------------------------------
constexpr int SZ_H16  = kNodes * 64;
constexpr int SZ_CV   = kNodes;
constexpr int SZ_HIST = kEdges;
constexpr int SZ_W1   = 64 * 160;
constexpr int SZ_W2   = 64 * 64;
constexpr int SZ_W3   = 64 * 64;
constexpr int SZ_NW1  = 64 * WRN;
constexpr int SZ_NW2  = 64 * WR2n;
constexpr int PREP_TOTAL = SZ_H16 + SZ_CV + SZ_HIST + SZ_W1 + SZ_W2 + SZ_W3 + SZ_NW1 + SZ_NW2;

__global__ __launch_bounds__(256) void prep_all(
    const float* __restrict__ h, const float* __restrict__ coord,
    const float* __restrict__ vel,
    const float* __restrict__ e_w1, const float* __restrict__ e_b1,
    const float* __restrict__ e_w2, const float* __restrict__ c_w1,
    const float* __restrict__ n_w1, const float* __restrict__ n_w2,
    const int* __restrict__ rows,
    _Float16* __restrict__ h16, _Float16* __restrict__ nodein,
    float4* __restrict__ cv, int* __restrict__ hist,
    _Float16* __restrict__ w1t, _Float16* __restrict__ w2t,
    _Float16* __restrict__ w3t, _Float16* __restrict__ nw1t,
    _Float16* __restrict__ nw2t)
{
  int i = blockIdx.x * 256 + threadIdx.x;
  if (i < SZ_H16) {
    _Float16 v = (_Float16)h[i];
    h16[i] = v;
    nodein[((size_t)(i >> 6)) * 128 + (i & 63)] = v;
    return;
  }
  i -= SZ_H16;
  if (i < SZ_CV) {
    cv[2 * i]     = make_float4(coord[3*i], coord[3*i+1], coord[3*i+2], 0.f);
    cv[2 * i + 1] = make_float4(vel[3*i],   vel[3*i+1],   vel[3*i+2],   0.f);
    return;
  }
  i -= SZ_CV;
  if (i < SZ_HIST) { atomicAdd(&hist[rows[i]], 1); return; }
  i -= SZ_HIST;
  if (i < SZ_W1) {
    int j = i / 160, k = i % 160;
    float v = (k < 131) ? e_w1[k * 64 + j] : (k == 131 ? e_b1[j] : 0.f);
    w1t[i] = (_Float16)v; return;
  }
  i -= SZ_W1;
  if (i < SZ_W2) { int j = i >> 6, k = i & 63; w2t[i] = (_Float16)e_w2[k * 64 + j]; return; }
  i -= SZ_W2;
  if (i < SZ_W3) { int j = i >> 6, k = i & 63; w3t[i] = (_Float16)c_w1[k * 64 + j]; return; }
  i -= SZ_W3;
  if (i < SZ_NW1) {
    int j = i / WRN, k = i % WRN;
    nw1t[i] = (k < 128) ? (_Float16)n_w1[k * 64 + j] : (_Float16)0.f; return;
  }
  i -= SZ_NW1;
  if (i < SZ_NW2) {
    int j = i / WR2n, k = i % WR2n;
    nw2t[i] = (k < 64) ? (_Float16)n_w2[k * 64 + j] : (_Float16)0.f;
  }
}

// ---------------------------------------------------------------------------
// CSR build: scan1 (block-local) + scan3 (inline bsum prefix) + scatter.
// Scatter writes ONE 32B record per CSR slot:
//   u0 = { pack(fx,fv), pack(fxv,1.0), (uint)r, (uint)c }
//   u1 = { cdx, cdy, cdz, 0 }
// ---------------------------------------------------------------------------
__global__ __launch_bounds__(1024) void scan1(const int* __restrict__ hist,
                                              int* __restrict__ rowstart,
                                              int* __restrict__ bsum) {
  int t = threadIdx.x;
  int i = blockIdx.x * 1024 + t;
  int lane = t & 63, wv = t >> 6;
  int v = (i < kNodes) ? hist[i] : 0;
  int acc = v;
#pragma unroll
  for (int off = 1; off < 64; off <<= 1) {
    int u = __shfl_up(acc, off);
    if (lane >= off) acc += u;
  }
  __shared__ int wsum[16];
  if (lane == 63) wsum[wv] = acc;
  __syncthreads();
  if (t < 16) {
    int ws = wsum[t];
#pragma unroll
    for (int off = 1; off < 16; off <<= 1) {
      int u = __shfl_up(ws, off);
      if (lane >= off) ws += u;
    }
    wsum[t] = ws;
  }
  __syncthreads();
  int woff = (wv == 0) ? 0 : wsum[wv - 1];
  if (i < kNodes) rowstart[i] = woff + acc - v;
  if (t == 1023) bsum[blockIdx.x] = wsum[15];
}

__global__ __launch_bounds__(1024) void scan3(int* __restrict__ rowstart,
                                              const int* __restrict__ bsum) {
  __shared__ int s_off;
  int b = blockIdx.x;
  if (threadIdx.x < 64) {
    int v = 0;
    for (int j = threadIdx.x; j < b; j += 64) v += bsum[j];
#pragma unroll
    for (int m = 32; m >= 1; m >>= 1) v += __shfl_xor(v, m);
    if (threadIdx.x == 0) s_off = v;
  }
  __syncthreads();
  int off = s_off;
  int i = b * 1024 + threadIdx.x;
  if (i < kNodes) rowstart[i] += off;
  if (b == gridDim.x - 1 && threadIdx.x == 0)
    rowstart[kNodes] = off + bsum[b];
}

__global__ __launch_bounds__(256) void scatter_kernel(
    const int* __restrict__ rows, const int* __restrict__ cols,
    const int* __restrict__ rowstart, int* __restrict__ cursor,
    const float4* __restrict__ cv,
    uint4* __restrict__ recbuf)   // 2 uint4 per record
{
  int e = blockIdx.x * 256 + threadIdx.x;
  if (e >= kEdges) return;
  int r = rows[e];
  int c = cols[e];
  int p = atomicAdd(&cursor[r], 1);
  int dst = rowstart[r] + p;

  float4 cr0 = cv[2 * r], cr1 = cv[2 * r + 1];
  float4 cc0 = cv[2 * c], cc1 = cv[2 * c + 1];
  float cdx = cr0.x - cc0.x, cdy = cr0.y - cc0.y, cdz = cr0.z - cc0.z;
  float vdx = cr1.x - cc1.x, vdy = cr1.y - cc1.y, vdz = cr1.z - cc1.z;
  float fx = sqrtf(cdx * cdx + cdy * cdy + cdz * cdz);
  float fv = sqrtf(vdx * vdx + vdy * vdy + vdz * vdz);
  float fxv = (cdx * vdx + cdy * vdy + cdz * vdz) / (fx * fv);
  union { _Float16 f[4]; uint2 u; } rp;
  rp.f[0] = (_Float16)fx;  rp.f[1] = (_Float16)fv;
  rp.f[2] = (_Float16)fxv; rp.f[3] = (_Float16)1.0f;

  recbuf[2 * dst]     = uint4{rp.u.x, rp.u.y, (unsigned)r, (unsigned)c};
  recbuf[2 * dst + 1] = uint4{__float_as_uint(cdx), __float_as_uint(cdy),
                              __float_as_uint(cdz), 0u};
}

// ---------------------------------------------------------------------------
// Edge kernel: persistent waves, zero loads in compute phases.
// PAIR-PIPELINED: two independent 16-edge groups interleaved phase-by-phase
// with separate sM slots, so each sM write->read latency is covered by ~20
// MFMAs of the partner group (the serial chain was 82% of the kernel at 4
// waves/SIMD). Per-group arithmetic order unchanged.
// ---------------------------------------------------------------------------
constexpr int EDGE_BLOCKS = 768;
constexpr int NWAVES  = EDGE_BLOCKS * 4;   // 3072
constexpr int NGROUPS = kEdges / 16;       // 50000

__global__ __launch_bounds__(256, 1) void egnn_edge_mfma(
    const _Float16* __restrict__ h16,
    const uint4* __restrict__ recbuf,
    const _Float16* __restrict__ w1t, const _Float16* __restrict__ w2t,
    const _Float16* __restrict__ w3t,
    const float* __restrict__ e_b2,
    const float* __restrict__ c_b1, const float* __restrict__ c_w,
    _Float16* __restrict__ mbuf, _Float16* __restrict__ transb16)
{
  __shared__ _Float16 sW2[64 * WL];
  __shared__ _Float16 sW3[64 * WL];
  __shared__ _Float16 sM[4][2][16][72];   // [wave][slot][edge][out]

  const int tid = threadIdx.x;
  const int w = tid >> 6, lane = tid & 63;
  const int g = lane >> 4, q = lane & 15;

  for (int idx = tid * 8; idx < 64 * 64; idx += 256 * 8) {
    int j = idx >> 6, k = idx & 63;
    *(f16x8*)&sW2[j * WL + k] = *(const f16x8*)&w2t[j * 64 + k];
    *(f16x8*)&sW3[j * WL + k] = *(const f16x8*)&w3t[j * 64 + k];
  }

  f16x8 W1[5][4];
#pragma unroll
  for (int ks = 0; ks < 5; ks++)
#pragma unroll
    for (int n = 0; n < 4; n++)
      W1[ks][n] = *(const f16x8*)&w1t[(n * 16 + q) * 160 + ks * 32 + g * 8];

  __syncthreads();

  const int W_id = blockIdx.x * 4 + w;
  const int g0   = (int)(((long long)NGROUPS * W_id) / NWAVES);
  const int gend = (int)(((long long)NGROUPS * (W_id + 1)) / NWAVES);
  const int n_it = gend - g0;
  if (n_it <= 0) return;

  _Float16* sm0 = &sM[w][0][0][0];
  _Float16* sm1 = &sM[w][1][0][0];

  uint4 bfA[4], bfB[4];
  uint4 radA, radB;
  float4 cdA, cdB;

  auto load_stage = [&](int grp, uint4 (&bf)[4], uint4& rad, float4& cd) {
    uint4 u0 = recbuf[(size_t)(grp * 16 + q) * 2];
    int r = (int)u0.z, c = (int)u0.w;
    const char* hr = (const char*)h16 + (size_t)r * 128;
    const char* hc = (const char*)h16 + (size_t)c * 128;
    bf[0] = *(const uint4*)(hr + g * 16);
    bf[1] = *(const uint4*)(hr + 64 + g * 16);
    bf[2] = *(const uint4*)(hc + g * 16);
    bf[3] = *(const uint4*)(hc + 64 + g * 16);
    rad = u0;
    if (lane < 16) {
      const uint4 u1 = recbuf[(size_t)(grp * 16 + lane) * 2 + 1];
      cd = make_float4(__uint_as_float(u1.x), __uint_as_float(u1.y),
                       __uint_as_float(u1.z), 0.f);
    }
  };

  // ---- phase: layer-1 MFMA + bias-folded relu -> m1 into sm ----
  auto phaseL1 = [&](const uint4 (&bf)[4], uint4 rad, _Float16* sm) {
    f32x4 acc[4] = {};
#pragma unroll
    for (int ks = 0; ks < 4; ks++) {
      f16x8 b = __builtin_bit_cast(f16x8, bf[ks]);
#pragma unroll
      for (int n = 0; n < 4; n++)
        acc[n] = __builtin_amdgcn_mfma_f32_16x16x32_f16(W1[ks][n], b, acc[n], 0, 0, 0);
    }
    {
      f16x8 b = {};
      if (lane < 16) {
        uint4 rz = rad; rz.z = 0u; rz.w = 0u;   // zero id slots (0*NaN hazard)
        b = __builtin_bit_cast(f16x8, rz);
      }
#pragma unroll
      for (int n = 0; n < 4; n++)
        acc[n] = __builtin_amdgcn_mfma_f32_16x16x32_f16(W1[4][n], b, acc[n], 0, 0, 0);
    }
#pragma unroll
    for (int n = 0; n < 4; n++) {
      float v0 = fmaxf(acc[n][0], 0.f), v1 = fmaxf(acc[n][1], 0.f);
      float v2 = fmaxf(acc[n][2], 0.f), v3 = fmaxf(acc[n][3], 0.f);
      union { _Float16 f[2]; unsigned u; } p01, p23;
      p01.f[0] = (_Float16)v0; p01.f[1] = (_Float16)v1;
      p23.f[0] = (_Float16)v2; p23.f[1] = (_Float16)v3;
      *(unsigned*)&sm[q * 72 + n * 16 + g * 4]     = p01.u;
      *(unsigned*)&sm[q * 72 + n * 16 + g * 4 + 2] = p23.u;
    }
  };

  // ---- phase: layer-2 MFMA (m1 from sm) + bias/relu -> m2 back into sm ----
  auto phaseL2 = [&](_Float16* sm) {
    f32x4 acc2[4] = {};
#pragma unroll
    for (int ks = 0; ks < 2; ks++) {
      f16x8 b = *(const f16x8*)&sm[q * 72 + ks * 32 + g * 8];
#pragma unroll
      for (int n = 0; n < 4; n++) {
        f16x8 a = *(const f16x8*)&sW2[(n * 16 + q) * WL + ks * 32 + g * 8];
        acc2[n] = __builtin_amdgcn_mfma_f32_16x16x32_f16(a, b, acc2[n], 0, 0, 0);
      }
    }
#pragma unroll
    for (int n = 0; n < 4; n++) {
      float4 b = *(const float4*)&e_b2[n * 16 + g * 4];
      float v0 = fmaxf(acc2[n][0] + b.x, 0.f);
      float v1 = fmaxf(acc2[n][1] + b.y, 0.f);
      float v2 = fmaxf(acc2[n][2] + b.z, 0.f);
      float v3 = fmaxf(acc2[n][3] + b.w, 0.f);
      union { _Float16 f[2]; unsigned u; } p01, p23;
      p01.f[0] = (_Float16)v0; p01.f[1] = (_Float16)v1;
      p23.f[0] = (_Float16)v2; p23.f[1] = (_Float16)v3;
      *(unsigned*)&sm[q * 72 + n * 16 + g * 4]     = p01.u;
      *(unsigned*)&sm[q * 72 + n * 16 + g * 4 + 2] = p23.u;
    }
  };

  // ---- phase: coalesced mbuf store (16 edges x 128B) ----
  auto phaseStore = [&](const _Float16* sm, int grp) {
    int el = lane >> 2, qq = lane & 3;
    f16x8 v0 = *(const f16x8*)&sm[el * 72 + qq * 16];
    f16x8 v1 = *(const f16x8*)&sm[el * 72 + qq * 16 + 8];
    size_t rowb = ((size_t)grp * 16 + el) * 64;
    *(f16x8*)&mbuf[rowb + qq * 16]     = v0;
    *(f16x8*)&mbuf[rowb + qq * 16 + 8] = v1;
  };

  // ---- phase: coord head + trans store ----
  auto phaseHead = [&](const _Float16* sm, float4 cd, int grp) {
    f32x4 acc3[4] = {};
#pragma unroll
    for (int ks = 0; ks < 2; ks++) {
      f16x8 b = *(const f16x8*)&sm[q * 72 + ks * 32 + g * 8];
#pragma unroll
      for (int n = 0; n < 4; n++) {
        f16x8 a = *(const f16x8*)&sW3[(n * 16 + q) * WL + ks * 32 + g * 8];
        acc3[n] = __builtin_amdgcn_mfma_f32_16x16x32_f16(a, b, acc3[n], 0, 0, 0);
      }
    }
    float s = 0.f;
#pragma unroll
    for (int n = 0; n < 4; n++) {
      float4 b  = *(const float4*)&c_b1[n * 16 + g * 4];
      float4 cw = *(const float4*)&c_w[n * 16 + g * 4];
      s += fmaxf(acc3[n][0] + b.x, 0.f) * cw.x;
      s += fmaxf(acc3[n][1] + b.y, 0.f) * cw.y;
      s += fmaxf(acc3[n][2] + b.z, 0.f) * cw.z;
      s += fmaxf(acc3[n][3] + b.w, 0.f) * cw.w;
    }
    s += __shfl_xor(s, 16);
    s += __shfl_xor(s, 32);
    if (lane < 16) {
      float t0 = fminf(fmaxf(cd.x * s, -100.0f), 100.0f);
      float t1 = fminf(fmaxf(cd.y * s, -100.0f), 100.0f);
      float t2 = fminf(fmaxf(cd.z * s, -100.0f), 100.0f);
      union { _Float16 f[4]; uint2 u; } tp;
      tp.f[0] = (_Float16)t0; tp.f[1] = (_Float16)t1;
      tp.f[2] = (_Float16)t2; tp.f[3] = (_Float16)0.f;
      *(uint2*)&transb16[(size_t)(grp * 16 + lane) * 4] = tp.u;
    }
  };

  // ---- pair-pipelined main loop ----
  load_stage(g0, bfA, radA, cdA);
  if (n_it > 1) load_stage(g0 + 1, bfB, radB, cdB);
  int it = 0;
  for (; it + 2 <= n_it; it += 2) {
    int gA = g0 + it, gB = g0 + it + 1;
    phaseL1(bfA, radA, sm0);
    phaseL1(bfB, radB, sm1);          // covers sm0 write->read latency
    float4 cdAc = cdA, cdBc = cdB;    // snapshot before prefetch overwrite
    if (it + 2 < n_it) load_stage(g0 + it + 2, bfA, radA, cdA);
    if (it + 3 < n_it) load_stage(g0 + it + 3, bfB, radB, cdB);
    phaseL2(sm0);                     // sm0 m1 ready (covered by L1(B)+loads)
    phaseL2(sm1);                     // covers sm0 m2 write->read
    phaseStore(sm0, gA);
    phaseStore(sm1, gB);
    phaseHead(sm0, cdAc, gA);
    phaseHead(sm1, cdBc, gB);
  }
  if (it < n_it) {                    // odd tail (group parity -> bfA)
    phaseL1(bfA, radA, sm0);
    phaseL2(sm0);
    phaseStore(sm0, g0 + it);
    phaseHead(sm0, cdA, g0 + it);
  }
}

// ---------------------------------------------------------------------------
// Gather: ONE WAVE PER NODE; rg/fg layout, 16 edge-rows in flight.
// ---------------------------------------------------------------------------
__global__ __launch_bounds__(256) void egnn_gather_kernel(
    const _Float16* __restrict__ mbuf, const _Float16* __restrict__ transb16,
    const int* __restrict__ rowstart,
    _Float16* __restrict__ nodein, float* __restrict__ coord_out)
{
  int node = blockIdx.x * 4 + (threadIdx.x >> 6);
  if (node >= kNodes) return;
  int lane = threadIdx.x & 63;
  int start = rowstart[node];
  int end = rowstart[node + 1];

  int rg = lane >> 3, fg = lane & 7;
  float acc[8] = {};
  int k = start;
  for (; k + 16 <= end; k += 16) {
    f16x8 v0 = *(const f16x8*)&mbuf[(size_t)(k + rg) * 64 + fg * 8];
    f16x8 v1 = *(const f16x8*)&mbuf[(size_t)(k + 8 + rg) * 64 + fg * 8];
#pragma unroll
    for (int u = 0; u < 8; u++) acc[u] += (float)v0[u] + (float)v1[u];
  }
  for (; k < end; k += 8) {
    int row = k + rg;
    if (row < end) {
      f16x8 v = *(const f16x8*)&mbuf[(size_t)row * 64 + fg * 8];
#pragma unroll
      for (int u = 0; u < 8; u++) acc[u] += (float)v[u];
    }
  }
#pragma unroll
  for (int off = 8; off < 64; off <<= 1) {
#pragma unroll
    for (int u = 0; u < 8; u++) acc[u] += __shfl_xor(acc[u], off);
  }
  if (lane < 8) {
    union { _Float16 f[8]; uint4 u4; } pk;
#pragma unroll
    for (int u = 0; u < 8; u++) pk.f[u] = (_Float16)acc[u];
    *(uint4*)&nodein[(size_t)node * 128 + 64 + lane * 8] = pk.u4;
  }

  float t0 = 0.0f, t1 = 0.0f, t2 = 0.0f;
  for (int kk = start + lane; kk < end; kk += 64) {
    union { uint2 u; _Float16 f[4]; } tv;
    tv.u = *(const uint2*)&transb16[(size_t)kk * 4];
    t0 += (float)tv.f[0]; t1 += (float)tv.f[1]; t2 += (float)tv.f[2];
  }
#pragma unroll
  for (int m = 32; m >= 1; m >>= 1) {
    t0 += __shfl_xor(t0, m);
    t1 += __shfl_xor(t1, m);
    t2 += __shfl_xor(t2, m);
  }
  if (lane == 0) {
    float cc = fmaxf((float)(end - start), 1.0f);
    coord_out[(size_t)node * 3 + 0] = t0 / cc;
    coord_out[(size_t)node * 3 + 1] = t1 / cc;
    coord_out[(size_t)node * 3 + 2] = t2 / cc;
  }
}

// ---------------------------------------------------------------------------
// Node MFMA kernel: block = 64 nodes, 4 waves; h_out direct from acc.
// ---------------------------------------------------------------------------
__global__ __launch_bounds__(256) void egnn_node_mfma(
    const _Float16* __restrict__ nodein,
    const _Float16* __restrict__ nw1t, const _Float16* __restrict__ nw2t,
    const float* __restrict__ n_b1, const float* __restrict__ n_b2,
    float* __restrict__ h_out)
{
  __shared__ _Float16 sN[64][WRN];
  __shared__ _Float16 sM[4][16][72];

  const int t = threadIdx.x;
  const int nb = blockIdx.x * 64;

  {
    int nl = t >> 2, p = t & 3;
    int node = nb + nl;
    uint4 z = {0, 0, 0, 0};
    uint4 v0 = z, v1 = z, v2 = z, v3 = z;
    if (node < kNodes) {
      const uint4* src = (const uint4*)(nodein + (size_t)node * 128);
      v0 = src[p * 4 + 0]; v1 = src[p * 4 + 1];
      v2 = src[p * 4 + 2]; v3 = src[p * 4 + 3];
    }
    *(uint4*)&sN[nl][p * 32 + 0]  = v0;
    *(uint4*)&sN[nl][p * 32 + 8]  = v1;
    *(uint4*)&sN[nl][p * 32 + 16] = v2;
    *(uint4*)&sN[nl][p * 32 + 24] = v3;
    if (p == 0) *(uint4*)&sN[nl][128] = z;
  }
  __syncthreads();

  const int lane = t & 63, w = t >> 6;
  const int g = lane >> 4, q = lane & 15;
  const int nrow = w * 16 + q;
  const int node = nb + nrow;

  f32x4 acc[4] = {};
#pragma unroll
  for (int ks = 0; ks < 4; ks++) {
    int kb = ks * 32 + g * 8;
    f16x8 bfrag = *(const f16x8*)&sN[nrow][kb];
#pragma unroll
    for (int n = 0; n < 4; n++) {
      f16x8 afrag = *(const f16x8*)&nw1t[(n * 16 + q) * WRN + kb];
      acc[n] = __builtin_amdgcn_mfma_f32_16x16x32_f16(afrag, bfrag, acc[n], 0, 0, 0);
    }
  }
#pragma unroll
  for (int n = 0; n < 4; n++) {
    float4 b = *(const float4*)&n_b1[n * 16 + g * 4];
    float v0 = fmaxf(acc[n][0] + b.x, 0.f);
    float v1 = fmaxf(acc[n][1] + b.y, 0.f);
    float v2 = fmaxf(acc[n][2] + b.z, 0.f);
    float v3 = fmaxf(acc[n][3] + b.w, 0.f);
    union { _Float16 f[2]; unsigned u; } p01, p23;
    p01.f[0] = (_Float16)v0; p01.f[1] = (_Float16)v1;
    p23.f[0] = (_Float16)v2; p23.f[1] = (_Float16)v3;
    *(unsigned*)&sM[w][q][n * 16 + g * 4]     = p01.u;
    *(unsigned*)&sM[w][q][n * 16 + g * 4 + 2] = p23.u;
  }

  f32x4 acc2[4] = {};
#pragma unroll
  for (int ks = 0; ks < 2; ks++) {
    int kb = ks * 32 + g * 8;
    f16x8 bfrag = *(const f16x8*)&sM[w][q][kb];
#pragma unroll
    for (int n = 0; n < 4; n++) {
      f16x8 afrag = *(const f16x8*)&nw2t[(n * 16 + q) * WR2n + kb];
      acc2[n] = __builtin_amdgcn_mfma_f32_16x16x32_f16(afrag, bfrag, acc2[n], 0, 0, 0);
    }
  }
  if (node < kNodes) {
#pragma unroll
    for (int n = 0; n < 4; n++) {
      float4 b = *(const float4*)&n_b2[n * 16 + g * 4];
      float4 o;
      o.x = acc2[n][0] + b.x;
      o.y = acc2[n][1] + b.y;
      o.z = acc2[n][2] + b.z;
      o.w = acc2[n][3] + b.w;
      *(float4*)&h_out[(size_t)node * 64 + n * 16 + g * 4] = o;
    }
  }
}

// ---------------------------------------------------------------------------
// Fallback (atomic) path — insurance if ws too small.
// ---------------------------------------------------------------------------
__global__ __launch_bounds__(256) void egnn_edge_atomic(
    const float* __restrict__ h, const float* __restrict__ coord,
    const float* __restrict__ vel,
    const int* __restrict__ rows, const int* __restrict__ cols,
    const float* __restrict__ e_w1, const float* __restrict__ e_b1,
    const float* __restrict__ e_w2, const float* __restrict__ e_b2,
    const float* __restrict__ c_w1, const float* __restrict__ c_b1,
    const float* __restrict__ c_w,
    float* __restrict__ agg, float* __restrict__ seg, float* __restrict__ cnt)
{
  int e = blockIdx.x * 256 + threadIdx.x;
  if (e >= kEdges) return;
  int r = rows[e];
  int c = cols[e];
  float cd0 = coord[r*3+0] - coord[c*3+0];
  float cd1 = coord[r*3+1] - coord[c*3+1];
  float cd2 = coord[r*3+2] - coord[c*3+2];
  float vd0 = vel[r*3+0] - vel[c*3+0];
  float vd1 = vel[r*3+1] - vel[c*3+1];
  float vd2 = vel[r*3+2] - vel[c*3+2];
  float fx = sqrtf(cd0*cd0 + cd1*cd1 + cd2*cd2);
  float fv = sqrtf(vd0*vd0 + vd1*vd1 + vd2*vd2);
  float fxv = (cd0*vd0 + cd1*vd1 + cd2*vd2) / (fx * fv);
  const float4* h4 = reinterpret_cast<const float4*>(h);
  float m1[kHid];
#pragma unroll
  for (int j = 0; j < kHid; j++) m1[j] = e_b1[j];
#pragma unroll 4
  for (int k4 = 0; k4 < 16; k4++) {
    float4 x4 = h4[r * 16 + k4];
    float xs[4] = {x4.x, x4.y, x4.z, x4.w};
#pragma unroll
    for (int u = 0; u < 4; u++) {
      float x = xs[u];
      const float* wp = e_w1 + (k4 * 4 + u) * kHid;
#pragma unroll
      for (int j = 0; j < kHid; j++) m1[j] += x * wp[j];
    }
  }
#pragma unroll 4
  for (int k4 = 0; k4 < 16; k4++) {
    float4 x4 = h4[c * 16 + k4];
    float xs[4] = {x4.x, x4.y, x4.z, x4.w};
#pragma unroll
    for (int u = 0; u < 4; u++) {
      float x = xs[u];
      const float* wp = e_w1 + (64 + k4 * 4 + u) * kHid;
#pragma unroll
      for (int j = 0; j < kHid; j++) m1[j] += x * wp[j];
    }
  }
  {
    float rad[3] = {fx, fv, fxv};
#pragma unroll
    for (int u = 0; u < 3; u++) {
      float x = rad[u];
      const float* wp = e_w1 + (128 + u) * kHid;
#pragma unroll
      for (int j = 0; j < kHid; j++) m1[j] += x * wp[j];
    }
  }
#pragma unroll
  for (int j = 0; j < kHid; j++) m1[j] = fmaxf(m1[j], 0.0f);
  float m2[kHid];
#pragma unroll
  for (int j = 0; j < kHid; j++) m2[j] = e_b2[j];
#pragma unroll
  for (int k = 0; k < kHid; k++) {
    float x = m1[k];
    const float* wp = e_w2 + k * kHid;
#pragma unroll
    for (int j = 0; j < kHid; j++) m2[j] += x * wp[j];
  }
#pragma unroll
  for (int j = 0; j < kHid; j++) m2[j] = fmaxf(m2[j], 0.0f);
  float s = 0.0f;
  {
    float tt[kHid];
#pragma unroll
    for (int j = 0; j < kHid; j++) tt[j] = c_b1[j];
#pragma unroll
    for (int k = 0; k < kHid; k++) {
      float x = m2[k];
      const float* wp = c_w1 + k * kHid;
#pragma unroll
      for (int j = 0; j < kHid; j++) tt[j] += x * wp[j];
    }
#pragma unroll
    for (int j = 0; j < kHid; j++) s += fmaxf(tt[j], 0.0f) * c_w[j];
  }
  float t0 = fminf(fmaxf(cd0 * s, -100.0f), 100.0f);
  float t1 = fminf(fmaxf(cd1 * s, -100.0f), 100.0f);
  float t2 = fminf(fmaxf(cd2 * s, -100.0f), 100.0f);
  atomicAdd(&seg[r * 3 + 0], t0);
  atomicAdd(&seg[r * 3 + 1], t1);
  atomicAdd(&seg[r * 3 + 2], t2);
  atomicAdd(&cnt[r], 1.0f);
#pragma unroll
  for (int j = 0; j < kHid; j++) atomicAdd(&agg[r * kHid + j], m2[j]);
}

__global__ __launch_bounds__(256) void egnn_node_fallback_kernel(
    const float* __restrict__ h, const float* __restrict__ agg,
    const float* __restrict__ seg, const float* __restrict__ cnt,
    const float* __restrict__ n_w1, const float* __restrict__ n_b1,
    const float* __restrict__ n_w2, const float* __restrict__ n_b2,
    float* __restrict__ h_out, float* __restrict__ coord_out)
{
  int i = blockIdx.x * 256 + threadIdx.x;
  if (i >= kNodes) return;
  const float4* h4 = reinterpret_cast<const float4*>(h);
  const float4* a4 = reinterpret_cast<const float4*>(agg);
  float t1[kHid];
#pragma unroll
  for (int j = 0; j < kHid; j++) t1[j] = n_b1[j];
#pragma unroll 4
  for (int k4 = 0; k4 < 16; k4++) {
    float4 x4 = h4[i * 16 + k4];
    float xs[4] = {x4.x, x4.y, x4.z, x4.w};
#pragma unroll
    for (int u = 0; u < 4; u++) {
      float x = xs[u];
      const float* wp = n_w1 + (k4 * 4 + u) * kHid;
#pragma unroll
      for (int j = 0; j < kHid; j++) t1[j] += x * wp[j];
    }
  }
#pragma unroll 4
  for (int k4 = 0; k4 < 16; k4++) {
    float4 x4 = a4[i * 16 + k4];
    float xs[4] = {x4.x, x4.y, x4.z, x4.w};
#pragma unroll
    for (int u = 0; u < 4; u++) {
      float x = xs[u];
      const float* wp = n_w1 + (64 + k4 * 4 + u) * kHid;
#pragma unroll
      for (int j = 0; j < kHid; j++) t1[j] += x * wp[j];
    }
  }
#pragma unroll
  for (int j = 0; j < kHid; j++) t1[j] = fmaxf(t1[j], 0.0f);
  float out[kHid];
#pragma unroll
  for (int j = 0; j < kHid; j++) out[j] = n_b2[j];
#pragma unroll
  for (int k = 0; k < kHid; k++) {
    float x = t1[k];
    const float* wp = n_w2 + k * kHid;
#pragma unroll
    for (int j = 0; j < kHid; j++) out[j] += x * wp[j];
  }
  float4* ho4 = reinterpret_cast<float4*>(h_out);
#pragma unroll
  for (int j4 = 0; j4 < 16; j4++) {
    ho4[i * 16 + j4] = make_float4(out[j4*4+0], out[j4*4+1], out[j4*4+2], out[j4*4+3]);
  }
  float cc = fmaxf(cnt[i], 1.0f);
  coord_out[i * 3 + 0] = seg[i * 3 + 0] / cc;
  coord_out[i * 3 + 1] = seg[i * 3 + 1] / cc;
  coord_out[i * 3 + 2] = seg[i * 3 + 2] / cc;
}

extern "C" void kernel_launch(void* const* d_in, const int* in_sizes, int n_in,
                              void* d_out, int out_size, void* d_ws, size_t ws_size,
                              hipStream_t stream) {
  const float* h     = (const float*)d_in[0];
  const float* coord = (const float*)d_in[1];
  const float* vel   = (const float*)d_in[2];
  const int* edge_index = (const int*)d_in[3];
  const float* e_w1 = (const float*)d_in[4];
  const float* e_b1 = (const float*)d_in[5];
  const float* e_w2 = (const float*)d_in[6];
  const float* e_b2 = (const float*)d_in[7];
  const float* n_w1 = (const float*)d_in[8];
  const float* n_b1 = (const float*)d_in[9];
  const float* n_w2 = (const float*)d_in[10];
  const float* n_b2 = (const float*)d_in[11];
  const float* c_w1 = (const float*)d_in[12];
  const float* c_b1 = (const float*)d_in[13];
  const float* c_w  = (const float*)d_in[14];

  const int* rows = edge_index;
  const int* cols = edge_index + kEdges;

  float* h_out = (float*)d_out;
  float* coord_out = h_out + (size_t)kNodes * kNF;

  // ---- workspace layout (bytes) ----
  const size_t off_mbuf   = 0;                                        // E*64*2
  const size_t off_trans  = off_mbuf   + (size_t)kEdges * kHid * 2;   // E*8 (f16x4)
  const size_t off_h16    = off_trans  + (size_t)kEdges * 8;          // N*64*2
  const size_t off_nodein = off_h16    + (size_t)kNodes * 64 * 2;     // N*128*2
  const size_t off_cv     = off_nodein + (size_t)kNodes * 128 * 2;    // N*32
  const size_t off_rec    = off_cv     + (size_t)kNodes * 32;         // E*32
  const size_t off_hist   = off_rec    + (size_t)kEdges * 32;         // N*4
  const size_t off_cursor = off_hist   + (size_t)kNodes * 4;          // N*4
  const size_t off_rowst  = off_cursor + (size_t)kNodes * 4;          // (N+1)*4 pad
  const size_t off_w1t    = off_rowst  + 200064;                      // 64*160*2
  const size_t off_w2t    = off_w1t    + (size_t)SZ_W1 * 2;
  const size_t off_w3t    = off_w2t    + (size_t)SZ_W2 * 2;
  const size_t off_nw1t   = off_w3t    + (size_t)SZ_W3 * 2;
  const size_t off_nw2t   = off_nw1t   + (size_t)SZ_NW1 * 2;
  const size_t off_bsum   = off_nw2t   + (size_t)SZ_NW2 * 2;
  const size_t need       = off_bsum   + 256;

  char* ws = (char*)d_ws;

  if (ws_size >= need) {
    _Float16* mbuf     = (_Float16*)(ws + off_mbuf);
    _Float16* transb16 = (_Float16*)(ws + off_trans);
    _Float16* h16      = (_Float16*)(ws + off_h16);
    _Float16* nodein   = (_Float16*)(ws + off_nodein);
    float4* cv         = (float4*)(ws + off_cv);
    uint4* recbuf      = (uint4*)(ws + off_rec);
    int* hist          = (int*)(ws + off_hist);
    int* cursor        = (int*)(ws + off_cursor);
    int* rowstart      = (int*)(ws + off_rowst);
    _Float16* w1t      = (_Float16*)(ws + off_w1t);
    _Float16* w2t      = (_Float16*)(ws + off_w2t);
    _Float16* w3t      = (_Float16*)(ws + off_w3t);
    _Float16* nw1t     = (_Float16*)(ws + off_nw1t);
    _Float16* nw2t     = (_Float16*)(ws + off_nw2t);
    int* bsum          = (int*)(ws + off_bsum);

    hipMemsetAsync(ws + off_hist, 0, (size_t)kNodes * 4 * 2, stream);  // hist+cursor

    prep_all<<<(PREP_TOTAL + 255) / 256, 256, 0, stream>>>(
        h, coord, vel, e_w1, e_b1, e_w2, c_w1, n_w1, n_w2, rows,
        h16, nodein, cv, hist, w1t, w2t, w3t, nw1t, nw2t);

    const int nb = (kNodes + 1023) / 1024;
    scan1<<<nb, 1024, 0, stream>>>(hist, rowstart, bsum);
    scan3<<<nb, 1024, 0, stream>>>(rowstart, bsum);
    scatter_kernel<<<(kEdges + 255) / 256, 256, 0, stream>>>(
        rows, cols, rowstart, cursor, cv, recbuf);

    egnn_edge_mfma<<<EDGE_BLOCKS, 256, 0, stream>>>(
        h16, recbuf, w1t, w2t, w3t,
        e_b2, c_b1, c_w, mbuf, transb16);

    egnn_gather_kernel<<<(kNodes + 3) / 4, 256, 0, stream>>>(
        mbuf, transb16, rowstart, nodein, coord_out);

    egnn_node_mfma<<<(kNodes + 63) / 64, 256, 0, stream>>>(
        nodein, nw1t, nw2t, n_b1, n_b2, h_out);
  } else {
    float* agg = (float*)d_ws;
    float* seg = agg + (size_t)kNodes * kHid;
    float* cnt = seg + (size_t)kNodes * 3;
    hipMemsetAsync(d_ws, 0, (size_t)kNodes * (kHid + 4) * sizeof(float), stream);

    egnn_edge_atomic<<<(kEdges + 255) / 256, 256, 0, stream>>>(
        h, coord, vel, rows, cols, e_w1, e_b1, e_w2, e_b2, c_w1, c_b1, c_w,
        agg, seg, cnt);

    egnn_node_fallback_kernel<<<(kNodes + 255) / 256, 256, 0, stream>>>(
        h, agg, seg, cnt, n_w1, n_b1, n_w2, n_b2, h_out, coord_out);
  }
}

// Round 17
// 192.255 us; speedup vs baseline: 1.1003x; 1.1003x over previous
//
#include <hip/hip_runtime.h>

constexpr int kNodes = 50000;
constexpr int kEdges = 800000;
constexpr int kNF  = 64;
constexpr int kHid = 64;

constexpr int WRN  = 136;  // nw1t / sN row stride (K=128 pad)
constexpr int WR2n = 72;   // nw2t / sM row stride
constexpr int WL   = 72;   // edge-kernel LDS weight row stride

typedef _Float16 f16x8 __attribute__((ext_vector_type(8)));
typedef float    f32x4 __attribute__((ext_vector_type(4)));

// ---------------------------------------------------------------------------
// Fused prep: h->f16 (+nodein low half), coord/vel pack, edge histogram,
// weight transposes. w1t has e_b1 folded at k=131.
// ---------------------------------------------------------------------------
constexpr int SZ_H16  = kNodes * 64;
constexpr int SZ_CV   = kNodes;
constexpr int SZ_HIST = kEdges;
constexpr int SZ_W1   = 64 * 160;
constexpr int SZ_W2   = 64 * 64;
constexpr int SZ_W3   = 64 * 64;
constexpr int SZ_NW1  = 64 * WRN;
constexpr int SZ_NW2  = 64 * WR2n;
constexpr int PREP_TOTAL = SZ_H16 + SZ_CV + SZ_HIST + SZ_W1 + SZ_W2 + SZ_W3 + SZ_NW1 + SZ_NW2;

__global__ __launch_bounds__(256) void prep_all(
    const float* __restrict__ h, const float* __restrict__ coord,
    const float* __restrict__ vel,
    const float* __restrict__ e_w1, const float* __restrict__ e_b1,
    const float* __restrict__ e_w2, const float* __restrict__ c_w1,
    const float* __restrict__ n_w1, const float* __restrict__ n_w2,
    const int* __restrict__ rows,
    _Float16* __restrict__ h16, _Float16* __restrict__ nodein,
    float4* __restrict__ cv, int* __restrict__ hist,
    _Float16* __restrict__ w1t, _Float16* __restrict__ w2t,
    _Float16* __restrict__ w3t, _Float16* __restrict__ nw1t,
    _Float16* __restrict__ nw2t)
{
  int i = blockIdx.x * 256 + threadIdx.x;
  if (i < SZ_H16) {
    _Float16 v = (_Float16)h[i];
    h16[i] = v;
    nodein[((size_t)(i >> 6)) * 128 + (i & 63)] = v;
    return;
  }
  i -= SZ_H16;
  if (i < SZ_CV) {
    cv[2 * i]     = make_float4(coord[3*i], coord[3*i+1], coord[3*i+2], 0.f);
    cv[2 * i + 1] = make_float4(vel[3*i],   vel[3*i+1],   vel[3*i+2],   0.f);
    return;
  }
  i -= SZ_CV;
  if (i < SZ_HIST) { atomicAdd(&hist[rows[i]], 1); return; }
  i -= SZ_HIST;
  if (i < SZ_W1) {
    int j = i / 160, k = i % 160;
    float v = (k < 131) ? e_w1[k * 64 + j] : (k == 131 ? e_b1[j] : 0.f);
    w1t[i] = (_Float16)v; return;
  }
  i -= SZ_W1;
  if (i < SZ_W2) { int j = i >> 6, k = i & 63; w2t[i] = (_Float16)e_w2[k * 64 + j]; return; }
  i -= SZ_W2;
  if (i < SZ_W3) { int j = i >> 6, k = i & 63; w3t[i] = (_Float16)c_w1[k * 64 + j]; return; }
  i -= SZ_W3;
  if (i < SZ_NW1) {
    int j = i / WRN, k = i % WRN;
    nw1t[i] = (k < 128) ? (_Float16)n_w1[k * 64 + j] : (_Float16)0.f; return;
  }
  i -= SZ_NW1;
  if (i < SZ_NW2) {
    int j = i / WR2n, k = i % WR2n;
    nw2t[i] = (k < 64) ? (_Float16)n_w2[k * 64 + j] : (_Float16)0.f;
  }
}

// ---------------------------------------------------------------------------
// CSR build: scan1 (block-local) + scan3 (inline bsum prefix) + scatter.
// Scatter writes ONE 32B record per CSR slot:
//   u0 = { pack(fx,fv), pack(fxv,1.0), (uint)r, (uint)c }
//   u1 = { cdx, cdy, cdz, 0 }
// ---------------------------------------------------------------------------
__global__ __launch_bounds__(1024) void scan1(const int* __restrict__ hist,
                                              int* __restrict__ rowstart,
                                              int* __restrict__ bsum) {
  int t = threadIdx.x;
  int i = blockIdx.x * 1024 + t;
  int lane = t & 63, wv = t >> 6;
  int v = (i < kNodes) ? hist[i] : 0;
  int acc = v;
#pragma unroll
  for (int off = 1; off < 64; off <<= 1) {
    int u = __shfl_up(acc, off);
    if (lane >= off) acc += u;
  }
  __shared__ int wsum[16];
  if (lane == 63) wsum[wv] = acc;
  __syncthreads();
  if (t < 16) {
    int ws = wsum[t];
#pragma unroll
    for (int off = 1; off < 16; off <<= 1) {
      int u = __shfl_up(ws, off);
      if (lane >= off) ws += u;
    }
    wsum[t] = ws;
  }
  __syncthreads();
  int woff = (wv == 0) ? 0 : wsum[wv - 1];
  if (i < kNodes) rowstart[i] = woff + acc - v;
  if (t == 1023) bsum[blockIdx.x] = wsum[15];
}

__global__ __launch_bounds__(1024) void scan3(int* __restrict__ rowstart,
                                              const int* __restrict__ bsum) {
  __shared__ int s_off;
  int b = blockIdx.x;
  if (threadIdx.x < 64) {
    int v = 0;
    for (int j = threadIdx.x; j < b; j += 64) v += bsum[j];
#pragma unroll
    for (int m = 32; m >= 1; m >>= 1) v += __shfl_xor(v, m);
    if (threadIdx.x == 0) s_off = v;
  }
  __syncthreads();
  int off = s_off;
  int i = b * 1024 + threadIdx.x;
  if (i < kNodes) rowstart[i] += off;
  if (b == gridDim.x - 1 && threadIdx.x == 0)
    rowstart[kNodes] = off + bsum[b];
}

__global__ __launch_bounds__(256) void scatter_kernel(
    const int* __restrict__ rows, const int* __restrict__ cols,
    const int* __restrict__ rowstart, int* __restrict__ cursor,
    const float4* __restrict__ cv,
    uint4* __restrict__ recbuf)   // 2 uint4 per record
{
  int e = blockIdx.x * 256 + threadIdx.x;
  if (e >= kEdges) return;
  int r = rows[e];
  int c = cols[e];
  int p = atomicAdd(&cursor[r], 1);
  int dst = rowstart[r] + p;

  float4 cr0 = cv[2 * r], cr1 = cv[2 * r + 1];
  float4 cc0 = cv[2 * c], cc1 = cv[2 * c + 1];
  float cdx = cr0.x - cc0.x, cdy = cr0.y - cc0.y, cdz = cr0.z - cc0.z;
  float vdx = cr1.x - cc1.x, vdy = cr1.y - cc1.y, vdz = cr1.z - cc1.z;
  float fx = sqrtf(cdx * cdx + cdy * cdy + cdz * cdz);
  float fv = sqrtf(vdx * vdx + vdy * vdy + vdz * vdz);
  float fxv = (cdx * vdx + cdy * vdy + cdz * vdz) / (fx * fv);
  union { _Float16 f[4]; uint2 u; } rp;
  rp.f[0] = (_Float16)fx;  rp.f[1] = (_Float16)fv;
  rp.f[2] = (_Float16)fxv; rp.f[3] = (_Float16)1.0f;

  recbuf[2 * dst]     = uint4{rp.u.x, rp.u.y, (unsigned)r, (unsigned)c};
  recbuf[2 * dst + 1] = uint4{__float_as_uint(cdx), __float_as_uint(cdy),
                              __float_as_uint(cdz), 0u};
}

// ---------------------------------------------------------------------------
// Edge kernel (round-15 validated optimum, 64us): persistent waves, zero
// loads in compute(), 32B record prefetch, W1 in VGPRs, W2/W3 in LDS,
// register double-buffer, coalesced sM->mbuf store. 1024 blocks = 4/CU at
// VGPR=124. Pair-pipelining (r16) and direct-store (r14) both regressed.
// ---------------------------------------------------------------------------
constexpr int EDGE_BLOCKS = 1024;
constexpr int NWAVES  = EDGE_BLOCKS * 4;   // 4096
constexpr int NGROUPS = kEdges / 16;       // 50000

__global__ __launch_bounds__(256, 2) void egnn_edge_mfma(
    const _Float16* __restrict__ h16,
    const uint4* __restrict__ recbuf,
    const _Float16* __restrict__ w1t, const _Float16* __restrict__ w2t,
    const _Float16* __restrict__ w3t,
    const float* __restrict__ e_b2,
    const float* __restrict__ c_b1, const float* __restrict__ c_w,
    _Float16* __restrict__ mbuf, _Float16* __restrict__ transb16)
{
  __shared__ _Float16 sW2[64 * WL];
  __shared__ _Float16 sW3[64 * WL];
  __shared__ _Float16 sM[4][16][72];

  const int tid = threadIdx.x;
  const int w = tid >> 6, lane = tid & 63;
  const int g = lane >> 4, q = lane & 15;

  for (int idx = tid * 8; idx < 64 * 64; idx += 256 * 8) {
    int j = idx >> 6, k = idx & 63;
    *(f16x8*)&sW2[j * WL + k] = *(const f16x8*)&w2t[j * 64 + k];
    *(f16x8*)&sW3[j * WL + k] = *(const f16x8*)&w3t[j * 64 + k];
  }

  f16x8 W1[5][4];
#pragma unroll
  for (int ks = 0; ks < 5; ks++)
#pragma unroll
    for (int n = 0; n < 4; n++)
      W1[ks][n] = *(const f16x8*)&w1t[(n * 16 + q) * 160 + ks * 32 + g * 8];

  __syncthreads();

  const int W_id = blockIdx.x * 4 + w;
  const int g0   = (int)(((long long)NGROUPS * W_id) / NWAVES);
  const int gend = (int)(((long long)NGROUPS * (W_id + 1)) / NWAVES);
  const int n_it = gend - g0;
  if (n_it <= 0) return;

  uint4 bfA[4], bfB[4];
  uint4 radA, radB;
  float4 cdA, cdB;

  auto load_stage = [&](int grp, uint4 (&bf)[4], uint4& rad, float4& cd) {
    uint4 u0 = recbuf[(size_t)(grp * 16 + q) * 2];
    int r = (int)u0.z, c = (int)u0.w;
    const char* hr = (const char*)h16 + (size_t)r * 128;
    const char* hc = (const char*)h16 + (size_t)c * 128;
    bf[0] = *(const uint4*)(hr + g * 16);
    bf[1] = *(const uint4*)(hr + 64 + g * 16);
    bf[2] = *(const uint4*)(hc + g * 16);
    bf[3] = *(const uint4*)(hc + 64 + g * 16);
    rad = u0;
    if (lane < 16) {
      const uint4 u1 = recbuf[(size_t)(grp * 16 + lane) * 2 + 1];
      cd = make_float4(__uint_as_float(u1.x), __uint_as_float(u1.y),
                       __uint_as_float(u1.z), 0.f);
    }
  };

  auto compute = [&](const uint4 (&bf)[4], uint4 rad, float4 cd, int grp) {
    // ---- layer 1, ksteps 0-3 ----
    f32x4 acc[4] = {};
#pragma unroll
    for (int ks = 0; ks < 4; ks++) {
      f16x8 b = __builtin_bit_cast(f16x8, bf[ks]);
#pragma unroll
      for (int n = 0; n < 4; n++)
        acc[n] = __builtin_amdgcn_mfma_f32_16x16x32_f16(W1[ks][n], b, acc[n], 0, 0, 0);
    }
    // ---- kstep 4: radial frag; zero id slots (0*NaN hazard) ----
    {
      f16x8 b = {};
      if (lane < 16) {
        uint4 rz = rad; rz.z = 0u; rz.w = 0u;
        b = __builtin_bit_cast(f16x8, rz);
      }
#pragma unroll
      for (int n = 0; n < 4; n++)
        acc[n] = __builtin_amdgcn_mfma_f32_16x16x32_f16(W1[4][n], b, acc[n], 0, 0, 0);
    }

#pragma unroll
    for (int n = 0; n < 4; n++) {
      float v0 = fmaxf(acc[n][0], 0.f), v1 = fmaxf(acc[n][1], 0.f);
      float v2 = fmaxf(acc[n][2], 0.f), v3 = fmaxf(acc[n][3], 0.f);
      union { _Float16 f[2]; unsigned u; } p01, p23;
      p01.f[0] = (_Float16)v0; p01.f[1] = (_Float16)v1;
      p23.f[0] = (_Float16)v2; p23.f[1] = (_Float16)v3;
      *(unsigned*)&sM[w][q][n * 16 + g * 4]     = p01.u;
      *(unsigned*)&sM[w][q][n * 16 + g * 4 + 2] = p23.u;
    }

    // ---- layer 2 ----
    f32x4 acc2[4] = {};
#pragma unroll
    for (int ks = 0; ks < 2; ks++) {
      f16x8 b = *(const f16x8*)&sM[w][q][ks * 32 + g * 8];
#pragma unroll
      for (int n = 0; n < 4; n++) {
        f16x8 a = *(const f16x8*)&sW2[(n * 16 + q) * WL + ks * 32 + g * 8];
        acc2[n] = __builtin_amdgcn_mfma_f32_16x16x32_f16(a, b, acc2[n], 0, 0, 0);
      }
    }
#pragma unroll
    for (int n = 0; n < 4; n++) {
      float4 b = *(const float4*)&e_b2[n * 16 + g * 4];
      float v0 = fmaxf(acc2[n][0] + b.x, 0.f);
      float v1 = fmaxf(acc2[n][1] + b.y, 0.f);
      float v2 = fmaxf(acc2[n][2] + b.z, 0.f);
      float v3 = fmaxf(acc2[n][3] + b.w, 0.f);
      union { _Float16 f[2]; unsigned u; } p01, p23;
      p01.f[0] = (_Float16)v0; p01.f[1] = (_Float16)v1;
      p23.f[0] = (_Float16)v2; p23.f[1] = (_Float16)v3;
      *(unsigned*)&sM[w][q][n * 16 + g * 4]     = p01.u;
      *(unsigned*)&sM[w][q][n * 16 + g * 4 + 2] = p23.u;
    }

    // ---- mbuf store (16 edges x 128B, coalesced cross-lane) ----
    {
      int el = lane >> 2, qq = lane & 3;
      f16x8 v0 = *(const f16x8*)&sM[w][el][qq * 16];
      f16x8 v1 = *(const f16x8*)&sM[w][el][qq * 16 + 8];
      size_t rowb = ((size_t)grp * 16 + el) * 64;
      *(f16x8*)&mbuf[rowb + qq * 16]     = v0;
      *(f16x8*)&mbuf[rowb + qq * 16 + 8] = v1;
    }

    // ---- coord head ----
    f32x4 acc3[4] = {};
#pragma unroll
    for (int ks = 0; ks < 2; ks++) {
      f16x8 b = *(const f16x8*)&sM[w][q][ks * 32 + g * 8];
#pragma unroll
      for (int n = 0; n < 4; n++) {
        f16x8 a = *(const f16x8*)&sW3[(n * 16 + q) * WL + ks * 32 + g * 8];
        acc3[n] = __builtin_amdgcn_mfma_f32_16x16x32_f16(a, b, acc3[n], 0, 0, 0);
      }
    }
    float s = 0.f;
#pragma unroll
    for (int n = 0; n < 4; n++) {
      float4 b  = *(const float4*)&c_b1[n * 16 + g * 4];
      float4 cw = *(const float4*)&c_w[n * 16 + g * 4];
      s += fmaxf(acc3[n][0] + b.x, 0.f) * cw.x;
      s += fmaxf(acc3[n][1] + b.y, 0.f) * cw.y;
      s += fmaxf(acc3[n][2] + b.z, 0.f) * cw.z;
      s += fmaxf(acc3[n][3] + b.w, 0.f) * cw.w;
    }
    s += __shfl_xor(s, 16);
    s += __shfl_xor(s, 32);
    if (lane < 16) {
      float t0 = fminf(fmaxf(cd.x * s, -100.0f), 100.0f);
      float t1 = fminf(fmaxf(cd.y * s, -100.0f), 100.0f);
      float t2 = fminf(fmaxf(cd.z * s, -100.0f), 100.0f);
      union { _Float16 f[4]; uint2 u; } tp;
      tp.f[0] = (_Float16)t0; tp.f[1] = (_Float16)t1;
      tp.f[2] = (_Float16)t2; tp.f[3] = (_Float16)0.f;
      *(uint2*)&transb16[(size_t)(grp * 16 + lane) * 4] = tp.u;
    }
  };

  load_stage(g0, bfA, radA, cdA);
  if (n_it > 1) load_stage(g0 + 1, bfB, radB, cdB);
  int it = 0;
  for (; it + 2 <= n_it; it += 2) {
    compute(bfA, radA, cdA, g0 + it);
    if (it + 2 < n_it) load_stage(g0 + it + 2, bfA, radA, cdA);
    compute(bfB, radB, cdB, g0 + it + 1);
    if (it + 3 < n_it) load_stage(g0 + it + 3, bfB, radB, cdB);
  }
  if (it < n_it) compute(bfA, radA, cdA, g0 + it);
}

// ---------------------------------------------------------------------------
// Gather: ONE WAVE PER NODE; rg/fg layout, 16 edge-rows in flight.
// ---------------------------------------------------------------------------
__global__ __launch_bounds__(256) void egnn_gather_kernel(
    const _Float16* __restrict__ mbuf, const _Float16* __restrict__ transb16,
    const int* __restrict__ rowstart,
    _Float16* __restrict__ nodein, float* __restrict__ coord_out)
{
  int node = blockIdx.x * 4 + (threadIdx.x >> 6);
  if (node >= kNodes) return;
  int lane = threadIdx.x & 63;
  int start = rowstart[node];
  int end = rowstart[node + 1];

  int rg = lane >> 3, fg = lane & 7;
  float acc[8] = {};
  int k = start;
  for (; k + 16 <= end; k += 16) {
    f16x8 v0 = *(const f16x8*)&mbuf[(size_t)(k + rg) * 64 + fg * 8];
    f16x8 v1 = *(const f16x8*)&mbuf[(size_t)(k + 8 + rg) * 64 + fg * 8];
#pragma unroll
    for (int u = 0; u < 8; u++) acc[u] += (float)v0[u] + (float)v1[u];
  }
  for (; k < end; k += 8) {
    int row = k + rg;
    if (row < end) {
      f16x8 v = *(const f16x8*)&mbuf[(size_t)row * 64 + fg * 8];
#pragma unroll
      for (int u = 0; u < 8; u++) acc[u] += (float)v[u];
    }
  }
#pragma unroll
  for (int off = 8; off < 64; off <<= 1) {
#pragma unroll
    for (int u = 0; u < 8; u++) acc[u] += __shfl_xor(acc[u], off);
  }
  if (lane < 8) {
    union { _Float16 f[8]; uint4 u4; } pk;
#pragma unroll
    for (int u = 0; u < 8; u++) pk.f[u] = (_Float16)acc[u];
    *(uint4*)&nodein[(size_t)node * 128 + 64 + lane * 8] = pk.u4;
  }

  float t0 = 0.0f, t1 = 0.0f, t2 = 0.0f;
  for (int kk = start + lane; kk < end; kk += 64) {
    union { uint2 u; _Float16 f[4]; } tv;
    tv.u = *(const uint2*)&transb16[(size_t)kk * 4];
    t0 += (float)tv.f[0]; t1 += (float)tv.f[1]; t2 += (float)tv.f[2];
  }
#pragma unroll
  for (int m = 32; m >= 1; m >>= 1) {
    t0 += __shfl_xor(t0, m);
    t1 += __shfl_xor(t1, m);
    t2 += __shfl_xor(t2, m);
  }
  if (lane == 0) {
    float cc = fmaxf((float)(end - start), 1.0f);
    coord_out[(size_t)node * 3 + 0] = t0 / cc;
    coord_out[(size_t)node * 3 + 1] = t1 / cc;
    coord_out[(size_t)node * 3 + 2] = t2 / cc;
  }
}

// ---------------------------------------------------------------------------
// Node MFMA kernel: block = 64 nodes, 4 waves; h_out direct from acc.
// ---------------------------------------------------------------------------
__global__ __launch_bounds__(256) void egnn_node_mfma(
    const _Float16* __restrict__ nodein,
    const _Float16* __restrict__ nw1t, const _Float16* __restrict__ nw2t,
    const float* __restrict__ n_b1, const float* __restrict__ n_b2,
    float* __restrict__ h_out)
{
  __shared__ _Float16 sN[64][WRN];
  __shared__ _Float16 sM[4][16][72];

  const int t = threadIdx.x;
  const int nb = blockIdx.x * 64;

  {
    int nl = t >> 2, p = t & 3;
    int node = nb + nl;
    uint4 z = {0, 0, 0, 0};
    uint4 v0 = z, v1 = z, v2 = z, v3 = z;
    if (node < kNodes) {
      const uint4* src = (const uint4*)(nodein + (size_t)node * 128);
      v0 = src[p * 4 + 0]; v1 = src[p * 4 + 1];
      v2 = src[p * 4 + 2]; v3 = src[p * 4 + 3];
    }
    *(uint4*)&sN[nl][p * 32 + 0]  = v0;
    *(uint4*)&sN[nl][p * 32 + 8]  = v1;
    *(uint4*)&sN[nl][p * 32 + 16] = v2;
    *(uint4*)&sN[nl][p * 32 + 24] = v3;
    if (p == 0) *(uint4*)&sN[nl][128] = z;
  }
  __syncthreads();

  const int lane = t & 63, w = t >> 6;
  const int g = lane >> 4, q = lane & 15;
  const int nrow = w * 16 + q;
  const int node = nb + nrow;

  f32x4 acc[4] = {};
#pragma unroll
  for (int ks = 0; ks < 4; ks++) {
    int kb = ks * 32 + g * 8;
    f16x8 bfrag = *(const f16x8*)&sN[nrow][kb];
#pragma unroll
    for (int n = 0; n < 4; n++) {
      f16x8 afrag = *(const f16x8*)&nw1t[(n * 16 + q) * WRN + kb];
      acc[n] = __builtin_amdgcn_mfma_f32_16x16x32_f16(afrag, bfrag, acc[n], 0, 0, 0);
    }
  }
#pragma unroll
  for (int n = 0; n < 4; n++) {
    float4 b = *(const float4*)&n_b1[n * 16 + g * 4];
    float v0 = fmaxf(acc[n][0] + b.x, 0.f);
    float v1 = fmaxf(acc[n][1] + b.y, 0.f);
    float v2 = fmaxf(acc[n][2] + b.z, 0.f);
    float v3 = fmaxf(acc[n][3] + b.w, 0.f);
    union { _Float16 f[2]; unsigned u; } p01, p23;
    p01.f[0] = (_Float16)v0; p01.f[1] = (_Float16)v1;
    p23.f[0] = (_Float16)v2; p23.f[1] = (_Float16)v3;
    *(unsigned*)&sM[w][q][n * 16 + g * 4]     = p01.u;
    *(unsigned*)&sM[w][q][n * 16 + g * 4 + 2] = p23.u;
  }

  f32x4 acc2[4] = {};
#pragma unroll
  for (int ks = 0; ks < 2; ks++) {
    int kb = ks * 32 + g * 8;
    f16x8 bfrag = *(const f16x8*)&sM[w][q][kb];
#pragma unroll
    for (int n = 0; n < 4; n++) {
      f16x8 afrag = *(const f16x8*)&nw2t[(n * 16 + q) * WR2n + kb];
      acc2[n] = __builtin_amdgcn_mfma_f32_16x16x32_f16(afrag, bfrag, acc2[n], 0, 0, 0);
    }
  }
  if (node < kNodes) {
#pragma unroll
    for (int n = 0; n < 4; n++) {
      float4 b = *(const float4*)&n_b2[n * 16 + g * 4];
      float4 o;
      o.x = acc2[n][0] + b.x;
      o.y = acc2[n][1] + b.y;
      o.z = acc2[n][2] + b.z;
      o.w = acc2[n][3] + b.w;
      *(float4*)&h_out[(size_t)node * 64 + n * 16 + g * 4] = o;
    }
  }
}

// ---------------------------------------------------------------------------
// Fallback (atomic) path — insurance if ws too small.
// ---------------------------------------------------------------------------
__global__ __launch_bounds__(256) void egnn_edge_atomic(
    const float* __restrict__ h, const float* __restrict__ coord,
    const float* __restrict__ vel,
    const int* __restrict__ rows, const int* __restrict__ cols,
    const float* __restrict__ e_w1, const float* __restrict__ e_b1,
    const float* __restrict__ e_w2, const float* __restrict__ e_b2,
    const float* __restrict__ c_w1, const float* __restrict__ c_b1,
    const float* __restrict__ c_w,
    float* __restrict__ agg, float* __restrict__ seg, float* __restrict__ cnt)
{
  int e = blockIdx.x * 256 + threadIdx.x;
  if (e >= kEdges) return;
  int r = rows[e];
  int c = cols[e];
  float cd0 = coord[r*3+0] - coord[c*3+0];
  float cd1 = coord[r*3+1] - coord[c*3+1];
  float cd2 = coord[r*3+2] - coord[c*3+2];
  float vd0 = vel[r*3+0] - vel[c*3+0];
  float vd1 = vel[r*3+1] - vel[c*3+1];
  float vd2 = vel[r*3+2] - vel[c*3+2];
  float fx = sqrtf(cd0*cd0 + cd1*cd1 + cd2*cd2);
  float fv = sqrtf(vd0*vd0 + vd1*vd1 + vd2*vd2);
  float fxv = (cd0*vd0 + cd1*vd1 + cd2*vd2) / (fx * fv);
  const float4* h4 = reinterpret_cast<const float4*>(h);
  float m1[kHid];
#pragma unroll
  for (int j = 0; j < kHid; j++) m1[j] = e_b1[j];
#pragma unroll 4
  for (int k4 = 0; k4 < 16; k4++) {
    float4 x4 = h4[r * 16 + k4];
    float xs[4] = {x4.x, x4.y, x4.z, x4.w};
#pragma unroll
    for (int u = 0; u < 4; u++) {
      float x = xs[u];
      const float* wp = e_w1 + (k4 * 4 + u) * kHid;
#pragma unroll
      for (int j = 0; j < kHid; j++) m1[j] += x * wp[j];
    }
  }
#pragma unroll 4
  for (int k4 = 0; k4 < 16; k4++) {
    float4 x4 = h4[c * 16 + k4];
    float xs[4] = {x4.x, x4.y, x4.z, x4.w};
#pragma unroll
    for (int u = 0; u < 4; u++) {
      float x = xs[u];
      const float* wp = e_w1 + (64 + k4 * 4 + u) * kHid;
#pragma unroll
      for (int j = 0; j < kHid; j++) m1[j] += x * wp[j];
    }
  }
  {
    float rad[3] = {fx, fv, fxv};
#pragma unroll
    for (int u = 0; u < 3; u++) {
      float x = rad[u];
      const float* wp = e_w1 + (128 + u) * kHid;
#pragma unroll
      for (int j = 0; j < kHid; j++) m1[j] += x * wp[j];
    }
  }
#pragma unroll
  for (int j = 0; j < kHid; j++) m1[j] = fmaxf(m1[j], 0.0f);
  float m2[kHid];
#pragma unroll
  for (int j = 0; j < kHid; j++) m2[j] = e_b2[j];
#pragma unroll
  for (int k = 0; k < kHid; k++) {
    float x = m1[k];
    const float* wp = e_w2 + k * kHid;
#pragma unroll
    for (int j = 0; j < kHid; j++) m2[j] += x * wp[j];
  }
#pragma unroll
  for (int j = 0; j < kHid; j++) m2[j] = fmaxf(m2[j], 0.0f);
  float s = 0.0f;
  {
    float tt[kHid];
#pragma unroll
    for (int j = 0; j < kHid; j++) tt[j] = c_b1[j];
#pragma unroll
    for (int k = 0; k < kHid; k++) {
      float x = m2[k];
      const float* wp = c_w1 + k * kHid;
#pragma unroll
      for (int j = 0; j < kHid; j++) tt[j] += x * wp[j];
    }
#pragma unroll
    for (int j = 0; j < kHid; j++) s += fmaxf(tt[j], 0.0f) * c_w[j];
  }
  float t0 = fminf(fmaxf(cd0 * s, -100.0f), 100.0f);
  float t1 = fminf(fmaxf(cd1 * s, -100.0f), 100.0f);
  float t2 = fminf(fmaxf(cd2 * s, -100.0f), 100.0f);
  atomicAdd(&seg[r * 3 + 0], t0);
  atomicAdd(&seg[r * 3 + 1], t1);
  atomicAdd(&seg[r * 3 + 2], t2);
  atomicAdd(&cnt[r], 1.0f);
#pragma unroll
  for (int j = 0; j < kHid; j++) atomicAdd(&agg[r * kHid + j], m2[j]);
}

__global__ __launch_bounds__(256) void egnn_node_fallback_kernel(
    const float* __restrict__ h, const float* __restrict__ agg,
    const float* __restrict__ seg, const float* __restrict__ cnt,
    const float* __restrict__ n_w1, const float* __restrict__ n_b1,
    const float* __restrict__ n_w2, const float* __restrict__ n_b2,
    float* __restrict__ h_out, float* __restrict__ coord_out)
{
  int i = blockIdx.x * 256 + threadIdx.x;
  if (i >= kNodes) return;
  const float4* h4 = reinterpret_cast<const float4*>(h);
  const float4* a4 = reinterpret_cast<const float4*>(agg);
  float t1[kHid];
#pragma unroll
  for (int j = 0; j < kHid; j++) t1[j] = n_b1[j];
#pragma unroll 4
  for (int k4 = 0; k4 < 16; k4++) {
    float4 x4 = h4[i * 16 + k4];
    float xs[4] = {x4.x, x4.y, x4.z, x4.w};
#pragma unroll
    for (int u = 0; u < 4; u++) {
      float x = xs[u];
      const float* wp = n_w1 + (k4 * 4 + u) * kHid;
#pragma unroll
      for (int j = 0; j < kHid; j++) t1[j] += x * wp[j];
    }
  }
#pragma unroll 4
  for (int k4 = 0; k4 < 16; k4++) {
    float4 x4 = a4[i * 16 + k4];
    float xs[4] = {x4.x, x4.y, x4.z, x4.w};
#pragma unroll
    for (int u = 0; u < 4; u++) {
      float x = xs[u];
      const float* wp = n_w1 + (64 + k4 * 4 + u) * kHid;
#pragma unroll
      for (int j = 0; j < kHid; j++) t1[j] += x * wp[j];
    }
  }
#pragma unroll
  for (int j = 0; j < kHid; j++) t1[j] = fmaxf(t1[j], 0.0f);
  float out[kHid];
#pragma unroll
  for (int j = 0; j < kHid; j++) out[j] = n_b2[j];
#pragma unroll
  for (int k = 0; k < kHid; k++) {
    float x = t1[k];
    const float* wp = n_w2 + k * kHid;
#pragma unroll
    for (int j = 0; j < kHid; j++) out[j] += x * wp[j];
  }
  float4* ho4 = reinterpret_cast<float4*>(h_out);
#pragma unroll
  for (int j4 = 0; j4 < 16; j4++) {
    ho4[i * 16 + j4] = make_float4(out[j4*4+0], out[j4*4+1], out[j4*4+2], out[j4*4+3]);
  }
  float cc = fmaxf(cnt[i], 1.0f);
  coord_out[i * 3 + 0] = seg[i * 3 + 0] / cc;
  coord_out[i * 3 + 1] = seg[i * 3 + 1] / cc;
  coord_out[i * 3 + 2] = seg[i * 3 + 2] / cc;
}

extern "C" void kernel_launch(void* const* d_in, const int* in_sizes, int n_in,
                              void* d_out, int out_size, void* d_ws, size_t ws_size,
                              hipStream_t stream) {
  const float* h     = (const float*)d_in[0];
  const float* coord = (const float*)d_in[1];
  const float* vel   = (const float*)d_in[2];
  const int* edge_index = (const int*)d_in[3];
  const float* e_w1 = (const float*)d_in[4];
  const float* e_b1 = (const float*)d_in[5];
  const float* e_w2 = (const float*)d_in[6];
  const float* e_b2 = (const float*)d_in[7];
  const float* n_w1 = (const float*)d_in[8];
  const float* n_b1 = (const float*)d_in[9];
  const float* n_w2 = (const float*)d_in[10];
  const float* n_b2 = (const float*)d_in[11];
  const float* c_w1 = (const float*)d_in[12];
  const float* c_b1 = (const float*)d_in[13];
  const float* c_w  = (const float*)d_in[14];

  const int* rows = edge_index;
  const int* cols = edge_index + kEdges;

  float* h_out = (float*)d_out;
  float* coord_out = h_out + (size_t)kNodes * kNF;

  // ---- workspace layout (bytes) ----
  const size_t off_mbuf   = 0;                                        // E*64*2
  const size_t off_trans  = off_mbuf   + (size_t)kEdges * kHid * 2;   // E*8 (f16x4)
  const size_t off_h16    = off_trans  + (size_t)kEdges * 8;          // N*64*2
  const size_t off_nodein = off_h16    + (size_t)kNodes * 64 * 2;     // N*128*2
  const size_t off_cv     = off_nodein + (size_t)kNodes * 128 * 2;    // N*32
  const size_t off_rec    = off_cv     + (size_t)kNodes * 32;         // E*32
  const size_t off_hist   = off_rec    + (size_t)kEdges * 32;         // N*4
  const size_t off_cursor = off_hist   + (size_t)kNodes * 4;          // N*4
  const size_t off_rowst  = off_cursor + (size_t)kNodes * 4;          // (N+1)*4 pad
  const size_t off_w1t    = off_rowst  + 200064;                      // 64*160*2
  const size_t off_w2t    = off_w1t    + (size_t)SZ_W1 * 2;
  const size_t off_w3t    = off_w2t    + (size_t)SZ_W2 * 2;
  const size_t off_nw1t   = off_w3t    + (size_t)SZ_W3 * 2;
  const size_t off_nw2t   = off_nw1t   + (size_t)SZ_NW1 * 2;
  const size_t off_bsum   = off_nw2t   + (size_t)SZ_NW2 * 2;
  const size_t need       = off_bsum   + 256;

  char* ws = (char*)d_ws;

  if (ws_size >= need) {
    _Float16* mbuf     = (_Float16*)(ws + off_mbuf);
    _Float16* transb16 = (_Float16*)(ws + off_trans);
    _Float16* h16      = (_Float16*)(ws + off_h16);
    _Float16* nodein   = (_Float16*)(ws + off_nodein);
    float4* cv         = (float4*)(ws + off_cv);
    uint4* recbuf      = (uint4*)(ws + off_rec);
    int* hist          = (int*)(ws + off_hist);
    int* cursor        = (int*)(ws + off_cursor);
    int* rowstart      = (int*)(ws + off_rowst);
    _Float16* w1t      = (_Float16*)(ws + off_w1t);
    _Float16* w2t      = (_Float16*)(ws + off_w2t);
    _Float16* w3t      = (_Float16*)(ws + off_w3t);
    _Float16* nw1t     = (_Float16*)(ws + off_nw1t);
    _Float16* nw2t     = (_Float16*)(ws + off_nw2t);
    int* bsum          = (int*)(ws + off_bsum);

    hipMemsetAsync(ws + off_hist, 0, (size_t)kNodes * 4 * 2, stream);  // hist+cursor

    prep_all<<<(PREP_TOTAL + 255) / 256, 256, 0, stream>>>(
        h, coord, vel, e_w1, e_b1, e_w2, c_w1, n_w1, n_w2, rows,
        h16, nodein, cv, hist, w1t, w2t, w3t, nw1t, nw2t);

    const int nb = (kNodes + 1023) / 1024;
    scan1<<<nb, 1024, 0, stream>>>(hist, rowstart, bsum);
    scan3<<<nb, 1024, 0, stream>>>(rowstart, bsum);
    scatter_kernel<<<(kEdges + 255) / 256, 256, 0, stream>>>(
        rows, cols, rowstart, cursor, cv, recbuf);

    egnn_edge_mfma<<<EDGE_BLOCKS, 256, 0, stream>>>(
        h16, recbuf, w1t, w2t, w3t,
        e_b2, c_b1, c_w, mbuf, transb16);

    egnn_gather_kernel<<<(kNodes + 3) / 4, 256, 0, stream>>>(
        mbuf, transb16, rowstart, nodein, coord_out);

    egnn_node_mfma<<<(kNodes + 63) / 64, 256, 0, stream>>>(
        nodein, nw1t, nw2t, n_b1, n_b2, h_out);
  } else {
    float* agg = (float*)d_ws;
    float* seg = agg + (size_t)kNodes * kHid;
    float* cnt = seg + (size_t)kNodes * 3;
    hipMemsetAsync(d_ws, 0, (size_t)kNodes * (kHid + 4) * sizeof(float), stream);

    egnn_edge_atomic<<<(kEdges + 255) / 256, 256, 0, stream>>>(
        h, coord, vel, rows, cols, e_w1, e_b1, e_w2, e_b2, c_w1, c_b1, c_w,
        agg, seg, cnt);

    egnn_node_fallback_kernel<<<(kNodes + 255) / 256, 256, 0, stream>>>(
        h, agg, seg, cnt, n_w1, n_b1, n_w2, n_b2, h_out, coord_out);
  }
}